// Round 13
// baseline (354.002 us; speedup 1.0000x reference)
//
#include <hip/hip_runtime.h>

typedef unsigned short u16;
typedef unsigned int   u32;
typedef unsigned long long u64;
typedef __attribute__((ext_vector_type(8))) short bf16x8;
typedef __attribute__((ext_vector_type(4))) float f32x4;

#define DEV static __device__ __forceinline__

DEV u16 f2bf(float f){ union{float f; u32 i;} v; v.f=f; u32 u=v.i;
                       return (u16)((u + 0x7FFFu + ((u>>16)&1u))>>16); }
DEV float bf2f(u16 u){ union{u32 i; float f;} v; v.i=((u32)u)<<16; return v.f; }
// LOAD-BEARING (R12 post-mortem): LDS stores are u16, reads are u32 — without the
// "memory" clobber the compiler's alias analysis reorders them (absmax=inf).
DEV void ldsfence(){ asm volatile("s_waitcnt lgkmcnt(0)" ::: "memory"); }

// ---- bias slab (f32): bin,bp1,bp2,ba1,ba2,bout ----
#define NBIAS 384
// ---- fragment buffer FB: [frag][lane][8] u16 ----
#define FB_P1 0
#define FB_P2 4
#define FB_A1 12
#define FB_A2 20
#define FB_IN 28
#define FB_LIN 36
#define FB_SRC 44
#define FB_DST 52
#define FB_OUT 60
#define NFRAG 68

DEV bf16x8 fb_load(const u16* __restrict__ FB, int frag, int lane){
  union{ uint4 u; bf16x8 v; } w;
  w.u = *(const uint4*)(FB + ((size_t)(frag*64+lane))*8);
  return w.v;
}
DEV bf16x8 lds_read_chunk(const u32* l32, int dw){
  union{ u32 d[4]; bf16x8 v; } u;
#pragma unroll
  for(int p=0;p<4;p++) u.d[p] = l32[dw+p];
  return u.v;
}

// ---------- prep: bias slab + per-lane fragment buffer ----------
__global__ __launch_bounds__(256) void k_prep(
  const float* __restrict__ Win, const float* __restrict__ Wlin,
  const float* __restrict__ Wsrc, const float* __restrict__ Wdst,
  const float* __restrict__ Wp1, const float* __restrict__ Wp2,
  const float* __restrict__ Wa1, const float* __restrict__ Wa2,
  const float* __restrict__ Wout,
  const float* __restrict__ bin, const float* __restrict__ bp1, const float* __restrict__ bp2,
  const float* __restrict__ ba1, const float* __restrict__ ba2, const float* __restrict__ bout,
  float* __restrict__ Bf, u16* __restrict__ FB)
{
  int idx = blockIdx.x*256 + threadIdx.x;
  if(idx < NBIAS){
    int which = idx >> 6, c = idx & 63;
    const float* b;
    switch(which){ case 0:b=bin;break; case 1:b=bp1;break; case 2:b=bp2;break;
                   case 3:b=ba1;break; case 4:b=ba2;break; default:b=bout;break; }
    Bf[idx] = b[c];
  } else if(idx < NBIAS + NFRAG*64){
    int j = idx - NBIAS;
    int frag = j >> 6, lane = j & 63;
    int t = lane & 15, q = lane >> 4;
    const float* src; int K = 64, nt, s;
    if(frag < 4){ src = Wp1; K = 3; nt = frag; s = 0; }
    else if(frag < 12){ int g=frag-4;  src=Wp2;  nt=g>>1; s=g&1; }
    else if(frag < 20){ int g=frag-12; src=Wa1;  nt=g>>1; s=g&1; }
    else if(frag < 28){ int g=frag-20; src=Wa2;  nt=g>>1; s=g&1; }
    else if(frag < 36){ int g=frag-28; src=Win;  nt=g>>1; s=g&1; }
    else if(frag < 44){ int g=frag-36; src=Wlin; nt=g>>1; s=g&1; }
    else if(frag < 52){ int g=frag-44; src=Wsrc; nt=g>>1; s=g&1; }
    else if(frag < 60){ int g=frag-52; src=Wdst; nt=g>>1; s=g&1; }
    else              { int g=frag-60; src=Wout; nt=g>>1; s=g&1; }
    u16* dst = FB + ((size_t)(frag*64+lane))*8;
#pragma unroll
    for(int jj=0;jj<8;jj++){
      int k = s*32 + q*8 + jj;
      dst[jj] = (k<K) ? f2bf(src[k*64 + nt*16 + t]) : (u16)0;
    }
  }
}

// ---------- node side, MFMA. vf permuted [node][t*4+nt]; asof/adof standard ----------
__global__ __launch_bounds__(256) void k_node_m(
  const float* __restrict__ x, const float* __restrict__ Bf, const u16* __restrict__ FB,
  float* __restrict__ vf, float* __restrict__ asof, float* __restrict__ adof,
  int N, int ntiles)
{
  __shared__ u16 sc16[4][16*66];
  int lane = threadIdx.x & 63, warp = threadIdx.x >> 6;
  int t = lane & 15, q = lane >> 4;
  int tile = blockIdx.x*4 + warp;
  if(tile >= ntiles) return;
  u16* lb = sc16[warp]; u32* lb32 = (u32*)lb;
  int r0 = tile*16;
  int row = r0 + t; if(row >= N) row = N-1;

  const float4* x4 = (const float4*)(x + (size_t)row*64);
  bf16x8 xa[2];
#pragma unroll
  for(int s=0;s<2;s++){
    float4 u0 = x4[s*8 + q*2], u1 = x4[s*8 + q*2 + 1];
    xa[s][0]=(short)f2bf(u0.x); xa[s][1]=(short)f2bf(u0.y);
    xa[s][2]=(short)f2bf(u0.z); xa[s][3]=(short)f2bf(u0.w);
    xa[s][4]=(short)f2bf(u1.x); xa[s][5]=(short)f2bf(u1.y);
    xa[s][6]=(short)f2bf(u1.z); xa[s][7]=(short)f2bf(u1.w);
  }
  f32x4 zero = {0.f,0.f,0.f,0.f};
  f32x4 acc[4];
#pragma unroll
  for(int nt=0;nt<4;nt++){
    acc[nt] = __builtin_amdgcn_mfma_f32_16x16x32_bf16(xa[0], fb_load(FB, FB_IN+nt*2+0, lane), zero, 0,0,0);
    acc[nt] = __builtin_amdgcn_mfma_f32_16x16x32_bf16(xa[1], fb_load(FB, FB_IN+nt*2+1, lane), acc[nt], 0,0,0);
  }
#pragma unroll
  for(int nt=0;nt<4;nt++)
#pragma unroll
    for(int r=0;r<4;r++)
      lb[(q*4+r)*66 + nt*16 + t] = f2bf(fmaxf(acc[nt][r] + Bf[nt*16+t], 0.f));
  ldsfence();
  bf16x8 h0 = lds_read_chunk(lb32, t*33 + q*4);
  bf16x8 h1 = lds_read_chunk(lb32, t*33 + 16 + q*4);

  // vf: permuted float4 stores
  {
    f32x4 av[4];
#pragma unroll
    for(int nt=0;nt<4;nt++){
      av[nt] = __builtin_amdgcn_mfma_f32_16x16x32_bf16(h0, fb_load(FB, FB_LIN+nt*2+0, lane), zero, 0,0,0);
      av[nt] = __builtin_amdgcn_mfma_f32_16x16x32_bf16(h1, fb_load(FB, FB_LIN+nt*2+1, lane), av[nt], 0,0,0);
    }
#pragma unroll
    for(int r=0;r<4;r++){
      int rr = r0 + q*4 + r;
      if(rr < N){
        float4 o; o.x=av[0][r]; o.y=av[1][r]; o.z=av[2][r]; o.w=av[3][r];
        *(float4*)(vf + (size_t)rr*64 + t*4) = o;
      }
    }
  }
  const int fb0[2] = {FB_SRC, FB_DST};
  float* Os[2] = {asof, adof};
#pragma unroll
  for(int mtx=0; mtx<2; mtx++){
    float* O = Os[mtx];
#pragma unroll
    for(int nt=0;nt<4;nt++){
      f32x4 a = __builtin_amdgcn_mfma_f32_16x16x32_bf16(h0, fb_load(FB, fb0[mtx]+nt*2+0, lane), zero, 0,0,0);
      a = __builtin_amdgcn_mfma_f32_16x16x32_bf16(h1, fb_load(FB, fb0[mtx]+nt*2+1, lane), a, 0,0,0);
#pragma unroll
      for(int r=0;r<4;r++){
        int rr = r0 + q*4 + r;
        if(rr < N) O[(size_t)rr*64 + nt*16 + t] = a[r];
      }
    }
  }
}

// ---------- CSR build ----------
__global__ __launch_bounds__(256) void k_hist(const int* __restrict__ ei, int* __restrict__ deg, int E){
  int e = blockIdx.x*256 + threadIdx.x;
  if(e < E) atomicAdd(&deg[ei[(size_t)E + e]], 1);
}

__global__ __launch_bounds__(256) void k_scanA(const int* __restrict__ deg,
    int* __restrict__ row_start, int* __restrict__ bsum, int N){
  __shared__ int b[256];
  int tid = threadIdx.x, i = blockIdx.x*256 + tid;
  int v = (i<N) ? deg[i] : 0;
  b[tid] = v; __syncthreads();
#pragma unroll
  for(int off=1; off<256; off<<=1){
    int u = (tid>=off) ? b[tid-off] : 0;
    __syncthreads(); b[tid] += u; __syncthreads();
  }
  if(i<N) row_start[i] = b[tid] - v;
  if(tid==255) bsum[blockIdx.x] = b[255];
}
__global__ __launch_bounds__(256) void k_scanB(int* __restrict__ bsum,
    int* __restrict__ bsoff, int* __restrict__ row_start, int nb, int N){
  __shared__ int b[256];
  int tid = threadIdx.x;
  int v = (tid<nb) ? bsum[tid] : 0;
  b[tid] = v; __syncthreads();
#pragma unroll
  for(int off=1; off<256; off<<=1){
    int u = (tid>=off) ? b[tid-off] : 0;
    __syncthreads(); b[tid] += u; __syncthreads();
  }
  if(tid<nb) bsoff[tid] = b[tid] - v;
  if(tid==255) row_start[N] = b[255];
}
__global__ __launch_bounds__(256) void k_scanC(int* __restrict__ row_start,
    const int* __restrict__ bsoff, int N){
  int i = blockIdx.x*256 + threadIdx.x;
  if(i<N) row_start[i] += bsoff[blockIdx.x];
}

__global__ __launch_bounds__(256) void k_scatter(const int* __restrict__ ei,
    const int* __restrict__ row_start, int* __restrict__ cursor,
    int2* __restrict__ pair, int E){
  int e = blockIdx.x*256 + threadIdx.x;
  if(e >= E) return;
  int d = ei[(size_t)E + e];
  int p = atomicAdd(&cursor[d], 1);
  int2 pr; pr.x = ei[e]; pr.y = d;
  pair[row_start[d] + p] = pr;
}

// ---------- segment flush ----------
DEV void flushseg(int d, float* numP, float* SP, const int* __restrict__ row_start,
                  float* __restrict__ num, float* __restrict__ S,
                  int lo, int hi, int q, int t){
  if(d < 0) return;
#pragma unroll
  for(int nt=0;nt<4;nt++){
    numP[nt] += __shfl_xor(numP[nt], 16, 64);
    numP[nt] += __shfl_xor(numP[nt], 32, 64);
    SP[nt]   += __shfl_xor(SP[nt],   16, 64);
    SP[nt]   += __shfl_xor(SP[nt],   32, 64);
  }
  bool partial = (row_start[d] < lo) || (row_start[d+1] > hi);
  if(q==0){
#pragma unroll
    for(int nt=0;nt<4;nt++){
      size_t off = (size_t)d*64 + nt*16 + t;
      if(partial){ atomicAdd(&num[off], numP[nt]); atomicAdd(&S[off], SP[nt]); }
      else       { num[off] = numP[nt]; S[off] = SP[nt]; }
    }
  }
#pragma unroll
  for(int nt=0;nt<4;nt++){ numP[nt]=0.f; SP[nt]=0.f; }
}

// ---------- segmented accumulate for one 16-edge tile ----------
DEV void agg_tile(int tbase, int hi_w, int lo_w, int did,
                  const float wv[4][4], const float pd[4][4],
                  int& cur_d, float* numP, float* SP,
                  const int* __restrict__ row_start,
                  float* __restrict__ num, float* __restrict__ S, int q, int t){
  int m = 0;
  while(m < 16){
    int d0 = __shfl(did, m, 64);
    u32 same = (u32)(__ballot(did == d0) & 0xFFFFull);
    u32 rest = ~(same >> m);
    int len = __ffs(rest) - 1;
    int m1 = m + len;
    if(d0 != cur_d){
      flushseg(cur_d, numP, SP, row_start, num, S, lo_w, hi_w, q, t);
      cur_d = d0;
    }
#pragma unroll
    for(int r=0;r<4;r++){
      int mm = q*4 + r;
      bool use = (mm >= m) && (mm < m1) && ((tbase+mm) < hi_w);
      if(use){
#pragma unroll
        for(int nt=0;nt<4;nt++){
          numP[nt] += wv[nt][r] * pd[r][nt];
          SP[nt]   += wv[nt][r];
        }
      }
    }
    m = m1;
  }
}

// ---------- packed edge pipeline: R9 structure (no hoist), int2 pair, fences ----------
// (256,2): (256,4) spills to scratch (R8). Hoisting ad/as raised VGPR 116->128 and
// cost ~10us (R11) — keep gathers at their use point.
__global__ __launch_bounds__(256,2) void k_edge_p2(
  const int* __restrict__ row_start, const int2* __restrict__ pair,
  const float* __restrict__ pos, const float* __restrict__ Bf, const u16* __restrict__ FB,
  const float* __restrict__ vf, const float* __restrict__ asof, const float* __restrict__ adof,
  float* __restrict__ S, float* __restrict__ num, int E, int nsuper, int spw)
{
  __shared__ u16 sc16[4][32*66];   // t1/u rows: 0-15 chain A, 16-31 chain B
  __shared__ u16 scf16[4][32*66];  // delta (bf16) rows
  int lane = threadIdx.x & 63, warp = threadIdx.x >> 6;
  int t = lane & 15, q = lane >> 4;
  int wid = blockIdx.x*4 + warp;
  int s0 = wid*spw, s1 = s0 + spw;
  if(s0 >= nsuper) return;
  if(s1 > nsuper) s1 = nsuper;
  int lo = s0*32, hi = s1*32; if(hi > E) hi = E;
  u16* lb = sc16[warp]; u32* lb32 = (u32*)lb;
  u16* lfw = scf16[warp];

  bf16x8 wp1f[4];
#pragma unroll
  for(int nt=0;nt<4;nt++) wp1f[nt] = fb_load(FB, FB_P1+nt, lane);
  float bp1f[4], bp2f[4], ba1f[4], ba2f[4];
#pragma unroll
  for(int nt=0;nt<4;nt++){
    bp1f[nt]=Bf[ 64+nt*16+t]; bp2f[nt]=Bf[128+nt*16+t];
    ba1f[nt]=Bf[192+nt*16+t]; ba2f[nt]=Bf[256+nt*16+t];
  }
  const float4* as4 = (const float4*)asof;
  const float4* ad4 = (const float4*)adof;
  f32x4 zero = {0.f,0.f,0.f,0.f};
  float numP[4] = {0,0,0,0}, SP[4] = {0,0,0,0};
  int cur_d = -1;

  for(int tb = lo; tb < hi; tb += 32){
    bool hasB = (tb+16) < hi;
    int ecA = tb + t;        if(ecA >= hi) ecA = hi-1;
    int ecB = tb + 16 + t;   if(ecB >= hi) ecB = hi-1;
    int2 spA = pair[ecA], spB = pair[ecB];
    int sidA = spA.x, didA = spA.y;
    int sidB = spB.x, didB = spB.y;

    // --- P1 (both chains) ---
    bf16x8 a1A, a1B;
#pragma unroll
    for(int j=0;j<8;j++){ a1A[j]=0; a1B[j]=0; }
    if(q==0){
      a1A[0] = (short)f2bf(pos[(size_t)didA*3+0] - pos[(size_t)sidA*3+0]);
      a1A[1] = (short)f2bf(pos[(size_t)didA*3+1] - pos[(size_t)sidA*3+1]);
      a1A[2] = (short)f2bf(pos[(size_t)didA*3+2] - pos[(size_t)sidA*3+2]);
      a1B[0] = (short)f2bf(pos[(size_t)didB*3+0] - pos[(size_t)sidB*3+0]);
      a1B[1] = (short)f2bf(pos[(size_t)didB*3+1] - pos[(size_t)sidB*3+1]);
      a1B[2] = (short)f2bf(pos[(size_t)didB*3+2] - pos[(size_t)sidB*3+2]);
    }
    f32x4 accA[4], accB[4];
#pragma unroll
    for(int nt=0;nt<4;nt++){
      accA[nt] = __builtin_amdgcn_mfma_f32_16x16x32_bf16(a1A, wp1f[nt], zero, 0,0,0);
      accB[nt] = __builtin_amdgcn_mfma_f32_16x16x32_bf16(a1B, wp1f[nt], zero, 0,0,0);
    }

    ldsfence();                     // WAR vs prev supertile's u reads
#pragma unroll
    for(int nt=0;nt<4;nt++)
#pragma unroll
      for(int r=0;r<4;r++){
        lb[(     q*4+r)*66 + nt*16 + t] = f2bf(fmaxf(accA[nt][r] + bp1f[nt], 0.f));
        lb[(16 + q*4+r)*66 + nt*16 + t] = f2bf(fmaxf(accB[nt][r] + bp1f[nt], 0.f));
      }
    ldsfence();
    bf16x8 atA0 = lds_read_chunk(lb32, (t   )*33 + q*4);
    bf16x8 atA1 = lds_read_chunk(lb32, (t   )*33 + 16 + q*4);
    bf16x8 atB0 = lds_read_chunk(lb32, (t+16)*33 + q*4);
    bf16x8 atB1 = lds_read_chunk(lb32, (t+16)*33 + 16 + q*4);

    // --- P2 -> delta (bf16 in LDS) ---
#pragma unroll
    for(int nt=0;nt<4;nt++){
      bf16x8 w0 = fb_load(FB, FB_P2+nt*2+0, lane);
      bf16x8 w1 = fb_load(FB, FB_P2+nt*2+1, lane);
      accA[nt] = __builtin_amdgcn_mfma_f32_16x16x32_bf16(atA0, w0, zero, 0,0,0);
      accA[nt] = __builtin_amdgcn_mfma_f32_16x16x32_bf16(atA1, w1, accA[nt], 0,0,0);
      accB[nt] = __builtin_amdgcn_mfma_f32_16x16x32_bf16(atB0, w0, zero, 0,0,0);
      accB[nt] = __builtin_amdgcn_mfma_f32_16x16x32_bf16(atB1, w1, accB[nt], 0,0,0);
    }
    ldsfence();                     // WAR vs prev supertile's delta reads
#pragma unroll
    for(int nt=0;nt<4;nt++)
#pragma unroll
      for(int r=0;r<4;r++){
        lfw[(     q*4+r)*66 + nt*16 + t] = f2bf(accA[nt][r] + bp2f[nt]);
        lfw[(16 + q*4+r)*66 + nt*16 + t] = f2bf(accB[nt][r] + bp2f[nt]);
      }
    ldsfence();

    // --- ali = a_dst - a_src + delta (gathers at use point) ---
    bf16x8 aliA[2], aliB[2];
#pragma unroll
    for(int s=0;s<2;s++){
      float4 dA0 = ad4[(size_t)didA*16 + s*8 + q*2], dA1 = ad4[(size_t)didA*16 + s*8 + q*2 + 1];
      float4 sA0 = as4[(size_t)sidA*16 + s*8 + q*2], sA1 = as4[(size_t)sidA*16 + s*8 + q*2 + 1];
      float4 dB0 = ad4[(size_t)didB*16 + s*8 + q*2], dB1 = ad4[(size_t)didB*16 + s*8 + q*2 + 1];
      float4 sB0 = as4[(size_t)sidB*16 + s*8 + q*2], sB1 = as4[(size_t)sidB*16 + s*8 + q*2 + 1];
      const u16* dlA = lfw + (t   )*66 + s*32 + q*8;
      const u16* dlB = lfw + (t+16)*66 + s*32 + q*8;
      aliA[s][0]=(short)f2bf(dA0.x - sA0.x + bf2f(dlA[0]));
      aliA[s][1]=(short)f2bf(dA0.y - sA0.y + bf2f(dlA[1]));
      aliA[s][2]=(short)f2bf(dA0.z - sA0.z + bf2f(dlA[2]));
      aliA[s][3]=(short)f2bf(dA0.w - sA0.w + bf2f(dlA[3]));
      aliA[s][4]=(short)f2bf(dA1.x - sA1.x + bf2f(dlA[4]));
      aliA[s][5]=(short)f2bf(dA1.y - sA1.y + bf2f(dlA[5]));
      aliA[s][6]=(short)f2bf(dA1.z - sA1.z + bf2f(dlA[6]));
      aliA[s][7]=(short)f2bf(dA1.w - sA1.w + bf2f(dlA[7]));
      aliB[s][0]=(short)f2bf(dB0.x - sB0.x + bf2f(dlB[0]));
      aliB[s][1]=(short)f2bf(dB0.y - sB0.y + bf2f(dlB[1]));
      aliB[s][2]=(short)f2bf(dB0.z - sB0.z + bf2f(dlB[2]));
      aliB[s][3]=(short)f2bf(dB0.w - sB0.w + bf2f(dlB[3]));
      aliB[s][4]=(short)f2bf(dB1.x - sB1.x + bf2f(dlB[4]));
      aliB[s][5]=(short)f2bf(dB1.y - sB1.y + bf2f(dlB[5]));
      aliB[s][6]=(short)f2bf(dB1.z - sB1.z + bf2f(dlB[6]));
      aliB[s][7]=(short)f2bf(dB1.w - sB1.w + bf2f(dlB[7]));
    }

    // --- attn L1 ---
#pragma unroll
    for(int nt=0;nt<4;nt++){
      bf16x8 w0 = fb_load(FB, FB_A1+nt*2+0, lane);
      bf16x8 w1 = fb_load(FB, FB_A1+nt*2+1, lane);
      accA[nt] = __builtin_amdgcn_mfma_f32_16x16x32_bf16(aliA[0], w0, zero, 0,0,0);
      accA[nt] = __builtin_amdgcn_mfma_f32_16x16x32_bf16(aliA[1], w1, accA[nt], 0,0,0);
      accB[nt] = __builtin_amdgcn_mfma_f32_16x16x32_bf16(aliB[0], w0, zero, 0,0,0);
      accB[nt] = __builtin_amdgcn_mfma_f32_16x16x32_bf16(aliB[1], w1, accB[nt], 0,0,0);
    }
    ldsfence();                     // WAR vs at reads (lb reuse)
#pragma unroll
    for(int nt=0;nt<4;nt++)
#pragma unroll
      for(int r=0;r<4;r++){
        lb[(     q*4+r)*66 + nt*16 + t] = f2bf(fmaxf(accA[nt][r] + ba1f[nt], 0.f));
        lb[(16 + q*4+r)*66 + nt*16 + t] = f2bf(fmaxf(accB[nt][r] + ba1f[nt], 0.f));
      }
    ldsfence();

    // batched v-gathers (overlap with u reads + A2 mfma)
    float4 vrawA[4], vrawB[4];
#pragma unroll
    for(int r=0;r<4;r++){
      int mm = q*4 + r;
      int sA = __shfl(sidA, mm, 64);
      int sB = __shfl(sidB, mm, 64);
      vrawA[r] = *(const float4*)(vf + (size_t)sA*64 + t*4);
      vrawB[r] = *(const float4*)(vf + (size_t)sB*64 + t*4);
    }

    bf16x8 auA0 = lds_read_chunk(lb32, (t   )*33 + q*4);
    bf16x8 auA1 = lds_read_chunk(lb32, (t   )*33 + 16 + q*4);
    bf16x8 auB0 = lds_read_chunk(lb32, (t+16)*33 + q*4);
    bf16x8 auB1 = lds_read_chunk(lb32, (t+16)*33 + 16 + q*4);

    // --- attn L2 -> w=exp ---
#pragma unroll
    for(int nt=0;nt<4;nt++){
      bf16x8 w0 = fb_load(FB, FB_A2+nt*2+0, lane);
      bf16x8 w1 = fb_load(FB, FB_A2+nt*2+1, lane);
      accA[nt] = __builtin_amdgcn_mfma_f32_16x16x32_bf16(auA0, w0, zero, 0,0,0);
      accA[nt] = __builtin_amdgcn_mfma_f32_16x16x32_bf16(auA1, w1, accA[nt], 0,0,0);
      accB[nt] = __builtin_amdgcn_mfma_f32_16x16x32_bf16(auB0, w0, zero, 0,0,0);
      accB[nt] = __builtin_amdgcn_mfma_f32_16x16x32_bf16(auB1, w1, accB[nt], 0,0,0);
    }
    float wvA[4][4], wvB[4][4], pdA[4][4], pdB[4][4];
#pragma unroll
    for(int nt=0;nt<4;nt++)
#pragma unroll
      for(int r=0;r<4;r++){
        wvA[nt][r] = ((tb + q*4 + r) < hi)      ? __expf(fminf(accA[nt][r] + ba2f[nt], 80.f)) : 0.f;
        wvB[nt][r] = ((tb + 16 + q*4 + r) < hi) ? __expf(fminf(accB[nt][r] + ba2f[nt], 80.f)) : 0.f;
      }
#pragma unroll
    for(int r=0;r<4;r++){
      float va[4] = {vrawA[r].x, vrawA[r].y, vrawA[r].z, vrawA[r].w};
      float vb[4] = {vrawB[r].x, vrawB[r].y, vrawB[r].z, vrawB[r].w};
#pragma unroll
      for(int nt=0;nt<4;nt++){
        pdA[r][nt] = va[nt] + bf2f(lfw[(     q*4+r)*66 + nt*16 + t]);
        pdB[r][nt] = vb[nt] + bf2f(lfw[(16 + q*4+r)*66 + nt*16 + t]);
      }
    }

    agg_tile(tb,      hi, lo, didA, wvA, pdA, cur_d, numP, SP, row_start, num, S, q, t);
    if(hasB)
      agg_tile(tb+16, hi, lo, didB, wvB, pdB, cur_d, numP, SP, row_start, num, S, q, t);
  }
  flushseg(cur_d, numP, SP, row_start, num, S, lo, hi, q, t);
}

// ---------- out = relu((num/S) @ Wout + bout), MFMA ----------
__global__ __launch_bounds__(256) void k_out_m(
  const float* __restrict__ num, const float* __restrict__ S,
  const float* __restrict__ Bf, const u16* __restrict__ FB,
  float* __restrict__ out, int N, int ntiles)
{
  int lane = threadIdx.x & 63, warp = threadIdx.x >> 6;
  int t = lane & 15, q = lane >> 4;
  int tile = blockIdx.x*4 + warp;
  if(tile >= ntiles) return;
  int r0 = tile*16;
  int row = r0 + t; if(row >= N) row = N-1;
  const float4* n4 = (const float4*)(num + (size_t)row*64);
  const float4* s4 = (const float4*)(S   + (size_t)row*64);
  bf16x8 af[2];
#pragma unroll
  for(int s=0;s<2;s++){
    float4 n0 = n4[s*8 + q*2], n1 = n4[s*8 + q*2 + 1];
    float4 s0 = s4[s*8 + q*2], s1 = s4[s*8 + q*2 + 1];
    af[s][0]=(short)f2bf(n0.x/(s0.x+1e-16f)); af[s][1]=(short)f2bf(n0.y/(s0.y+1e-16f));
    af[s][2]=(short)f2bf(n0.z/(s0.z+1e-16f)); af[s][3]=(short)f2bf(n0.w/(s0.w+1e-16f));
    af[s][4]=(short)f2bf(n1.x/(s1.x+1e-16f)); af[s][5]=(short)f2bf(n1.y/(s1.y+1e-16f));
    af[s][6]=(short)f2bf(n1.z/(s1.z+1e-16f)); af[s][7]=(short)f2bf(n1.w/(s1.w+1e-16f));
  }
  f32x4 zero = {0.f,0.f,0.f,0.f};
#pragma unroll
  for(int nt=0;nt<4;nt++){
    f32x4 a = __builtin_amdgcn_mfma_f32_16x16x32_bf16(af[0], fb_load(FB, FB_OUT+nt*2+0, lane), zero, 0,0,0);
    a = __builtin_amdgcn_mfma_f32_16x16x32_bf16(af[1], fb_load(FB, FB_OUT+nt*2+1, lane), a, 0,0,0);
    float b = Bf[320 + nt*16 + t];
#pragma unroll
    for(int r=0;r<4;r++){
      int rr = r0 + q*4 + r;
      if(rr < N) out[(size_t)rr*64 + nt*16 + t] = fmaxf(a[r] + b, 0.f);
    }
  }
}

extern "C" void kernel_launch(void* const* d_in, const int* in_sizes, int n_in,
                              void* d_out, int out_size, void* d_ws, size_t ws_size,
                              hipStream_t stream){
  const float* x   =(const float*)d_in[0];
  const float* pos =(const float*)d_in[1];
  const int*   ei  =(const int*)d_in[2];
  const float* Win =(const float*)d_in[3];  const float* bin=(const float*)d_in[4];
  const float* Wlin=(const float*)d_in[5];  const float* Wsrc=(const float*)d_in[6];
  const float* Wdst=(const float*)d_in[7];
  const float* Wp1 =(const float*)d_in[8];  const float* bp1=(const float*)d_in[9];
  const float* Wp2 =(const float*)d_in[10]; const float* bp2=(const float*)d_in[11];
  const float* Wa1 =(const float*)d_in[12]; const float* ba1=(const float*)d_in[13];
  const float* Wa2 =(const float*)d_in[14]; const float* ba2=(const float*)d_in[15];
  const float* Wout=(const float*)d_in[16]; const float* bout=(const float*)d_in[17];
  int N = in_sizes[0]/64;
  int E = in_sizes[2]/2;

  float* Bf   = (float*)d_ws;
  u16*   FB   = (u16*)(Bf + NBIAS);
  float* vf   = (float*)(FB + (size_t)NFRAG*64*8);
  float* asof = vf   + (size_t)N*64;
  float* adof = asof + (size_t)N*64;
  float* S    = adof + (size_t)N*64;
  float* num  = S    + (size_t)N*64;
  int* deg       = (int*)(num + (size_t)N*64);
  int* cursor    = deg + N;
  int* row_start = cursor + N;
  int* bsum      = row_start + (N+1);
  int* bsoff     = bsum + 256;
  int2* pair     = (int2*)(bsoff + 256);

  int ntiles = (N+15)/16;
  int nsuper = (E+31)/32;
  int total_waves = 4096;
  int spw = (nsuper + total_waves - 1) / total_waves;
  int nwaves = (nsuper + spw - 1) / spw;
  int eblocks = (nwaves + 3) / 4;
  int nscb = (N+255)/256;

  hipMemsetAsync(deg, 0, (size_t)2*N*sizeof(int), stream);
  hipMemsetAsync(S, 0, (size_t)N*64*2*sizeof(float), stream);
  k_prep<<<dim3(19), dim3(256), 0, stream>>>(Win,Wlin,Wsrc,Wdst,Wp1,Wp2,Wa1,Wa2,Wout,
                                             bin,bp1,bp2,ba1,ba2,bout, Bf, FB);
  k_node_m<<<dim3((ntiles+3)/4), dim3(256), 0, stream>>>(x, Bf, FB, vf, asof, adof, N, ntiles);
  k_hist<<<dim3((E+255)/256), dim3(256), 0, stream>>>(ei, deg, E);
  k_scanA<<<dim3(nscb), dim3(256), 0, stream>>>(deg, row_start, bsum, N);
  k_scanB<<<dim3(1),    dim3(256), 0, stream>>>(bsum, bsoff, row_start, nscb, N);
  k_scanC<<<dim3(nscb), dim3(256), 0, stream>>>(row_start, bsoff, N);
  k_scatter<<<dim3((E+255)/256), dim3(256), 0, stream>>>(ei, row_start, cursor, pair, E);
  k_edge_p2<<<dim3(eblocks), dim3(256), 0, stream>>>(row_start, pair, pos, Bf, FB,
                                                     vf, asof, adof, S, num, E, nsuper, spw);
  k_out_m<<<dim3((ntiles+3)/4), dim3(256), 0, stream>>>(num, S, Bf, FB, (float*)d_out, N, ntiles);
}

// Round 14
// 342.218 us; speedup vs baseline: 1.0344x; 1.0344x over previous
//
#include <hip/hip_runtime.h>

typedef unsigned short u16;
typedef unsigned int   u32;
typedef unsigned long long u64;
typedef __attribute__((ext_vector_type(8))) short bf16x8;
typedef __attribute__((ext_vector_type(4))) float f32x4;

#define DEV static __device__ __forceinline__

DEV u16 f2bf(float f){ union{float f; u32 i;} v; v.f=f; u32 u=v.i;
                       return (u16)((u + 0x7FFFu + ((u>>16)&1u))>>16); }
DEV float bf2f(u16 u){ union{u32 i; float f;} v; v.i=((u32)u)<<16; return v.f; }
// LOAD-BEARING (R12 post-mortem): LDS stores are u16, reads are u32 — without the
// "memory" clobber the compiler's alias analysis reorders them (absmax=inf).
DEV void ldsfence(){ asm volatile("s_waitcnt lgkmcnt(0)" ::: "memory"); }

// ---- bias slab (f32): bin,bp1,bp2,ba1,ba2,bout ----
#define NBIAS 384
// ---- fragment buffer FB: [frag][lane][8] u16 ----
#define FB_P1 0
#define FB_P2 4
#define FB_A1 12
#define FB_A2 20
#define FB_IN 28
#define FB_LIN 36
#define FB_SRC 44
#define FB_DST 52
#define FB_OUT 60
#define NFRAG 68

DEV bf16x8 fb_load(const u16* __restrict__ FB, int frag, int lane){
  union{ uint4 u; bf16x8 v; } w;
  w.u = *(const uint4*)(FB + ((size_t)(frag*64+lane))*8);
  return w.v;
}
DEV bf16x8 lds_read_chunk(const u32* l32, int dw){
  union{ u32 d[4]; bf16x8 v; } u;
#pragma unroll
  for(int p=0;p<4;p++) u.d[p] = l32[dw+p];
  return u.v;
}

// ---------- prep: bias slab + per-lane fragment buffer ----------
__global__ __launch_bounds__(256) void k_prep(
  const float* __restrict__ Win, const float* __restrict__ Wlin,
  const float* __restrict__ Wsrc, const float* __restrict__ Wdst,
  const float* __restrict__ Wp1, const float* __restrict__ Wp2,
  const float* __restrict__ Wa1, const float* __restrict__ Wa2,
  const float* __restrict__ Wout,
  const float* __restrict__ bin, const float* __restrict__ bp1, const float* __restrict__ bp2,
  const float* __restrict__ ba1, const float* __restrict__ ba2, const float* __restrict__ bout,
  float* __restrict__ Bf, u16* __restrict__ FB)
{
  int idx = blockIdx.x*256 + threadIdx.x;
  if(idx < NBIAS){
    int which = idx >> 6, c = idx & 63;
    const float* b;
    switch(which){ case 0:b=bin;break; case 1:b=bp1;break; case 2:b=bp2;break;
                   case 3:b=ba1;break; case 4:b=ba2;break; default:b=bout;break; }
    Bf[idx] = b[c];
  } else if(idx < NBIAS + NFRAG*64){
    int j = idx - NBIAS;
    int frag = j >> 6, lane = j & 63;
    int t = lane & 15, q = lane >> 4;
    const float* src; int K = 64, nt, s;
    if(frag < 4){ src = Wp1; K = 3; nt = frag; s = 0; }
    else if(frag < 12){ int g=frag-4;  src=Wp2;  nt=g>>1; s=g&1; }
    else if(frag < 20){ int g=frag-12; src=Wa1;  nt=g>>1; s=g&1; }
    else if(frag < 28){ int g=frag-20; src=Wa2;  nt=g>>1; s=g&1; }
    else if(frag < 36){ int g=frag-28; src=Win;  nt=g>>1; s=g&1; }
    else if(frag < 44){ int g=frag-36; src=Wlin; nt=g>>1; s=g&1; }
    else if(frag < 52){ int g=frag-44; src=Wsrc; nt=g>>1; s=g&1; }
    else if(frag < 60){ int g=frag-52; src=Wdst; nt=g>>1; s=g&1; }
    else              { int g=frag-60; src=Wout; nt=g>>1; s=g&1; }
    u16* dst = FB + ((size_t)(frag*64+lane))*8;
#pragma unroll
    for(int jj=0;jj<8;jj++){
      int k = s*32 + q*8 + jj;
      dst[jj] = (k<K) ? f2bf(src[k*64 + nt*16 + t]) : (u16)0;
    }
  }
}

// ---------- node side, MFMA. vf/asof/adof stored BF16 (halves edge gather lines).
// vf permuted [node][t*4+nt] (uint2 = 4 bf16); asof/adof standard [node][64] bf16.
__global__ __launch_bounds__(256) void k_node_m(
  const float* __restrict__ x, const float* __restrict__ Bf, const u16* __restrict__ FB,
  u16* __restrict__ vf, u16* __restrict__ asof, u16* __restrict__ adof,
  int N, int ntiles)
{
  __shared__ u16 sc16[4][16*66];
  int lane = threadIdx.x & 63, warp = threadIdx.x >> 6;
  int t = lane & 15, q = lane >> 4;
  int tile = blockIdx.x*4 + warp;
  if(tile >= ntiles) return;
  u16* lb = sc16[warp]; u32* lb32 = (u32*)lb;
  int r0 = tile*16;
  int row = r0 + t; if(row >= N) row = N-1;

  const float4* x4 = (const float4*)(x + (size_t)row*64);
  bf16x8 xa[2];
#pragma unroll
  for(int s=0;s<2;s++){
    float4 u0 = x4[s*8 + q*2], u1 = x4[s*8 + q*2 + 1];
    xa[s][0]=(short)f2bf(u0.x); xa[s][1]=(short)f2bf(u0.y);
    xa[s][2]=(short)f2bf(u0.z); xa[s][3]=(short)f2bf(u0.w);
    xa[s][4]=(short)f2bf(u1.x); xa[s][5]=(short)f2bf(u1.y);
    xa[s][6]=(short)f2bf(u1.z); xa[s][7]=(short)f2bf(u1.w);
  }
  f32x4 zero = {0.f,0.f,0.f,0.f};
  f32x4 acc[4];
#pragma unroll
  for(int nt=0;nt<4;nt++){
    acc[nt] = __builtin_amdgcn_mfma_f32_16x16x32_bf16(xa[0], fb_load(FB, FB_IN+nt*2+0, lane), zero, 0,0,0);
    acc[nt] = __builtin_amdgcn_mfma_f32_16x16x32_bf16(xa[1], fb_load(FB, FB_IN+nt*2+1, lane), acc[nt], 0,0,0);
  }
#pragma unroll
  for(int nt=0;nt<4;nt++)
#pragma unroll
    for(int r=0;r<4;r++)
      lb[(q*4+r)*66 + nt*16 + t] = f2bf(fmaxf(acc[nt][r] + Bf[nt*16+t], 0.f));
  ldsfence();
  bf16x8 h0 = lds_read_chunk(lb32, t*33 + q*4);
  bf16x8 h1 = lds_read_chunk(lb32, t*33 + 16 + q*4);

  // vf: permuted uint2 stores (4 bf16)
  {
    f32x4 av[4];
#pragma unroll
    for(int nt=0;nt<4;nt++){
      av[nt] = __builtin_amdgcn_mfma_f32_16x16x32_bf16(h0, fb_load(FB, FB_LIN+nt*2+0, lane), zero, 0,0,0);
      av[nt] = __builtin_amdgcn_mfma_f32_16x16x32_bf16(h1, fb_load(FB, FB_LIN+nt*2+1, lane), av[nt], 0,0,0);
    }
#pragma unroll
    for(int r=0;r<4;r++){
      int rr = r0 + q*4 + r;
      if(rr < N){
        uint2 o;
        o.x = (u32)f2bf(av[0][r]) | ((u32)f2bf(av[1][r]) << 16);
        o.y = (u32)f2bf(av[2][r]) | ((u32)f2bf(av[3][r]) << 16);
        *(uint2*)(vf + (size_t)rr*64 + t*4) = o;
      }
    }
  }
  const int fb0[2] = {FB_SRC, FB_DST};
  u16* Os[2] = {asof, adof};
#pragma unroll
  for(int mtx=0; mtx<2; mtx++){
    u16* O = Os[mtx];
#pragma unroll
    for(int nt=0;nt<4;nt++){
      f32x4 a = __builtin_amdgcn_mfma_f32_16x16x32_bf16(h0, fb_load(FB, fb0[mtx]+nt*2+0, lane), zero, 0,0,0);
      a = __builtin_amdgcn_mfma_f32_16x16x32_bf16(h1, fb_load(FB, fb0[mtx]+nt*2+1, lane), a, 0,0,0);
#pragma unroll
      for(int r=0;r<4;r++){
        int rr = r0 + q*4 + r;
        if(rr < N) O[(size_t)rr*64 + nt*16 + t] = f2bf(a[r]);
      }
    }
  }
}

// ---------- CSR build ----------
__global__ __launch_bounds__(256) void k_hist(const int* __restrict__ ei, int* __restrict__ deg, int E){
  int e = blockIdx.x*256 + threadIdx.x;
  if(e < E) atomicAdd(&deg[ei[(size_t)E + e]], 1);
}

__global__ __launch_bounds__(256) void k_scanA(const int* __restrict__ deg,
    int* __restrict__ row_start, int* __restrict__ bsum, int N){
  __shared__ int b[256];
  int tid = threadIdx.x, i = blockIdx.x*256 + tid;
  int v = (i<N) ? deg[i] : 0;
  b[tid] = v; __syncthreads();
#pragma unroll
  for(int off=1; off<256; off<<=1){
    int u = (tid>=off) ? b[tid-off] : 0;
    __syncthreads(); b[tid] += u; __syncthreads();
  }
  if(i<N) row_start[i] = b[tid] - v;
  if(tid==255) bsum[blockIdx.x] = b[255];
}
__global__ __launch_bounds__(256) void k_scanB(int* __restrict__ bsum,
    int* __restrict__ bsoff, int* __restrict__ row_start, int nb, int N){
  __shared__ int b[256];
  int tid = threadIdx.x;
  int v = (tid<nb) ? bsum[tid] : 0;
  b[tid] = v; __syncthreads();
#pragma unroll
  for(int off=1; off<256; off<<=1){
    int u = (tid>=off) ? b[tid-off] : 0;
    __syncthreads(); b[tid] += u; __syncthreads();
  }
  if(tid<nb) bsoff[tid] = b[tid] - v;
  if(tid==255) row_start[N] = b[255];
}
__global__ __launch_bounds__(256) void k_scanC(int* __restrict__ row_start,
    const int* __restrict__ bsoff, int N){
  int i = blockIdx.x*256 + threadIdx.x;
  if(i<N) row_start[i] += bsoff[blockIdx.x];
}

__global__ __launch_bounds__(256) void k_scatter(const int* __restrict__ ei,
    const int* __restrict__ row_start, int* __restrict__ cursor,
    int2* __restrict__ pair, int E){
  int e = blockIdx.x*256 + threadIdx.x;
  if(e >= E) return;
  int d = ei[(size_t)E + e];
  int p = atomicAdd(&cursor[d], 1);
  int2 pr; pr.x = ei[e]; pr.y = d;
  pair[row_start[d] + p] = pr;
}

// ---------- segment flush ----------
DEV void flushseg(int d, float* numP, float* SP, const int* __restrict__ row_start,
                  float* __restrict__ num, float* __restrict__ S,
                  int lo, int hi, int q, int t){
  if(d < 0) return;
#pragma unroll
  for(int nt=0;nt<4;nt++){
    numP[nt] += __shfl_xor(numP[nt], 16, 64);
    numP[nt] += __shfl_xor(numP[nt], 32, 64);
    SP[nt]   += __shfl_xor(SP[nt],   16, 64);
    SP[nt]   += __shfl_xor(SP[nt],   32, 64);
  }
  bool partial = (row_start[d] < lo) || (row_start[d+1] > hi);
  if(q==0){
#pragma unroll
    for(int nt=0;nt<4;nt++){
      size_t off = (size_t)d*64 + nt*16 + t;
      if(partial){ atomicAdd(&num[off], numP[nt]); atomicAdd(&S[off], SP[nt]); }
      else       { num[off] = numP[nt]; S[off] = SP[nt]; }
    }
  }
#pragma unroll
  for(int nt=0;nt<4;nt++){ numP[nt]=0.f; SP[nt]=0.f; }
}

// ---------- segmented accumulate for one 16-edge tile ----------
DEV void agg_tile(int tbase, int hi_w, int lo_w, int did,
                  const float wv[4][4], const float pd[4][4],
                  int& cur_d, float* numP, float* SP,
                  const int* __restrict__ row_start,
                  float* __restrict__ num, float* __restrict__ S, int q, int t){
  int m = 0;
  while(m < 16){
    int d0 = __shfl(did, m, 64);
    u32 same = (u32)(__ballot(did == d0) & 0xFFFFull);
    u32 rest = ~(same >> m);
    int len = __ffs(rest) - 1;
    int m1 = m + len;
    if(d0 != cur_d){
      flushseg(cur_d, numP, SP, row_start, num, S, lo_w, hi_w, q, t);
      cur_d = d0;
    }
#pragma unroll
    for(int r=0;r<4;r++){
      int mm = q*4 + r;
      bool use = (mm >= m) && (mm < m1) && ((tbase+mm) < hi_w);
      if(use){
#pragma unroll
        for(int nt=0;nt<4;nt++){
          numP[nt] += wv[nt][r] * pd[r][nt];
          SP[nt]   += wv[nt][r];
        }
      }
    }
    m = m1;
  }
}

// ---------- packed edge pipeline: R13 structure, bf16 gathers (half the lines) ----------
// (256,2): (256,4) spills to scratch (R8). Gathers at use point (R11: hoist cost 10us).
__global__ __launch_bounds__(256,2) void k_edge_p2(
  const int* __restrict__ row_start, const int2* __restrict__ pair,
  const float* __restrict__ pos, const float* __restrict__ Bf, const u16* __restrict__ FB,
  const u16* __restrict__ vf, const u16* __restrict__ asof, const u16* __restrict__ adof,
  float* __restrict__ S, float* __restrict__ num, int E, int nsuper, int spw)
{
  __shared__ u16 sc16[4][32*66];   // t1/u rows: 0-15 chain A, 16-31 chain B
  __shared__ u16 scf16[4][32*66];  // delta (bf16) rows
  int lane = threadIdx.x & 63, warp = threadIdx.x >> 6;
  int t = lane & 15, q = lane >> 4;
  int wid = blockIdx.x*4 + warp;
  int s0 = wid*spw, s1 = s0 + spw;
  if(s0 >= nsuper) return;
  if(s1 > nsuper) s1 = nsuper;
  int lo = s0*32, hi = s1*32; if(hi > E) hi = E;
  u16* lb = sc16[warp]; u32* lb32 = (u32*)lb;
  u16* lfw = scf16[warp];

  bf16x8 wp1f[4];
#pragma unroll
  for(int nt=0;nt<4;nt++) wp1f[nt] = fb_load(FB, FB_P1+nt, lane);
  float bp1f[4], bp2f[4], ba1f[4], ba2f[4];
#pragma unroll
  for(int nt=0;nt<4;nt++){
    bp1f[nt]=Bf[ 64+nt*16+t]; bp2f[nt]=Bf[128+nt*16+t];
    ba1f[nt]=Bf[192+nt*16+t]; ba2f[nt]=Bf[256+nt*16+t];
  }
  const uint4* as8 = (const uint4*)asof;   // 8 bf16 per uint4; row = 8 uint4
  const uint4* ad8 = (const uint4*)adof;
  const uint2* v2  = (const uint2*)vf;     // 4 bf16 per uint2; row = 16 uint2
  f32x4 zero = {0.f,0.f,0.f,0.f};
  float numP[4] = {0,0,0,0}, SP[4] = {0,0,0,0};
  int cur_d = -1;

  for(int tb = lo; tb < hi; tb += 32){
    bool hasB = (tb+16) < hi;
    int ecA = tb + t;        if(ecA >= hi) ecA = hi-1;
    int ecB = tb + 16 + t;   if(ecB >= hi) ecB = hi-1;
    int2 spA = pair[ecA], spB = pair[ecB];
    int sidA = spA.x, didA = spA.y;
    int sidB = spB.x, didB = spB.y;

    // --- P1 (both chains) ---
    bf16x8 a1A, a1B;
#pragma unroll
    for(int j=0;j<8;j++){ a1A[j]=0; a1B[j]=0; }
    if(q==0){
      a1A[0] = (short)f2bf(pos[(size_t)didA*3+0] - pos[(size_t)sidA*3+0]);
      a1A[1] = (short)f2bf(pos[(size_t)didA*3+1] - pos[(size_t)sidA*3+1]);
      a1A[2] = (short)f2bf(pos[(size_t)didA*3+2] - pos[(size_t)sidA*3+2]);
      a1B[0] = (short)f2bf(pos[(size_t)didB*3+0] - pos[(size_t)sidB*3+0]);
      a1B[1] = (short)f2bf(pos[(size_t)didB*3+1] - pos[(size_t)sidB*3+1]);
      a1B[2] = (short)f2bf(pos[(size_t)didB*3+2] - pos[(size_t)sidB*3+2]);
    }
    f32x4 accA[4], accB[4];
#pragma unroll
    for(int nt=0;nt<4;nt++){
      accA[nt] = __builtin_amdgcn_mfma_f32_16x16x32_bf16(a1A, wp1f[nt], zero, 0,0,0);
      accB[nt] = __builtin_amdgcn_mfma_f32_16x16x32_bf16(a1B, wp1f[nt], zero, 0,0,0);
    }

    ldsfence();                     // WAR vs prev supertile's u reads
#pragma unroll
    for(int nt=0;nt<4;nt++)
#pragma unroll
      for(int r=0;r<4;r++){
        lb[(     q*4+r)*66 + nt*16 + t] = f2bf(fmaxf(accA[nt][r] + bp1f[nt], 0.f));
        lb[(16 + q*4+r)*66 + nt*16 + t] = f2bf(fmaxf(accB[nt][r] + bp1f[nt], 0.f));
      }
    ldsfence();
    bf16x8 atA0 = lds_read_chunk(lb32, (t   )*33 + q*4);
    bf16x8 atA1 = lds_read_chunk(lb32, (t   )*33 + 16 + q*4);
    bf16x8 atB0 = lds_read_chunk(lb32, (t+16)*33 + q*4);
    bf16x8 atB1 = lds_read_chunk(lb32, (t+16)*33 + 16 + q*4);

    // --- P2 -> delta (bf16 in LDS) ---
#pragma unroll
    for(int nt=0;nt<4;nt++){
      bf16x8 w0 = fb_load(FB, FB_P2+nt*2+0, lane);
      bf16x8 w1 = fb_load(FB, FB_P2+nt*2+1, lane);
      accA[nt] = __builtin_amdgcn_mfma_f32_16x16x32_bf16(atA0, w0, zero, 0,0,0);
      accA[nt] = __builtin_amdgcn_mfma_f32_16x16x32_bf16(atA1, w1, accA[nt], 0,0,0);
      accB[nt] = __builtin_amdgcn_mfma_f32_16x16x32_bf16(atB0, w0, zero, 0,0,0);
      accB[nt] = __builtin_amdgcn_mfma_f32_16x16x32_bf16(atB1, w1, accB[nt], 0,0,0);
    }
    ldsfence();                     // WAR vs prev supertile's delta reads
#pragma unroll
    for(int nt=0;nt<4;nt++)
#pragma unroll
      for(int r=0;r<4;r++){
        lfw[(     q*4+r)*66 + nt*16 + t] = f2bf(accA[nt][r] + bp2f[nt]);
        lfw[(16 + q*4+r)*66 + nt*16 + t] = f2bf(accB[nt][r] + bp2f[nt]);
      }
    ldsfence();

    // --- ali = a_dst - a_src + delta; ad/as gathered as bf16x8 chunks (1 uint4 each) ---
    bf16x8 aliA[2], aliB[2];
#pragma unroll
    for(int s=0;s<2;s++){
      union{ uint4 u; u16 h[8]; } dAh, sAh, dBh, sBh;
      dAh.u = ad8[(size_t)didA*8 + s*4 + q];
      sAh.u = as8[(size_t)sidA*8 + s*4 + q];
      dBh.u = ad8[(size_t)didB*8 + s*4 + q];
      sBh.u = as8[(size_t)sidB*8 + s*4 + q];
      const u16* dlA = lfw + (t   )*66 + s*32 + q*8;
      const u16* dlB = lfw + (t+16)*66 + s*32 + q*8;
#pragma unroll
      for(int j=0;j<8;j++){
        aliA[s][j] = (short)f2bf(bf2f(dAh.h[j]) - bf2f(sAh.h[j]) + bf2f(dlA[j]));
        aliB[s][j] = (short)f2bf(bf2f(dBh.h[j]) - bf2f(sBh.h[j]) + bf2f(dlB[j]));
      }
    }

    // --- attn L1 ---
#pragma unroll
    for(int nt=0;nt<4;nt++){
      bf16x8 w0 = fb_load(FB, FB_A1+nt*2+0, lane);
      bf16x8 w1 = fb_load(FB, FB_A1+nt*2+1, lane);
      accA[nt] = __builtin_amdgcn_mfma_f32_16x16x32_bf16(aliA[0], w0, zero, 0,0,0);
      accA[nt] = __builtin_amdgcn_mfma_f32_16x16x32_bf16(aliA[1], w1, accA[nt], 0,0,0);
      accB[nt] = __builtin_amdgcn_mfma_f32_16x16x32_bf16(aliB[0], w0, zero, 0,0,0);
      accB[nt] = __builtin_amdgcn_mfma_f32_16x16x32_bf16(aliB[1], w1, accB[nt], 0,0,0);
    }
    ldsfence();                     // WAR vs at reads (lb reuse)
#pragma unroll
    for(int nt=0;nt<4;nt++)
#pragma unroll
      for(int r=0;r<4;r++){
        lb[(     q*4+r)*66 + nt*16 + t] = f2bf(fmaxf(accA[nt][r] + ba1f[nt], 0.f));
        lb[(16 + q*4+r)*66 + nt*16 + t] = f2bf(fmaxf(accB[nt][r] + ba1f[nt], 0.f));
      }
    ldsfence();

    // batched v-gathers: one uint2 (4 bf16) per (r,chain)
    uint2 vrawA[4], vrawB[4];
#pragma unroll
    for(int r=0;r<4;r++){
      int mm = q*4 + r;
      int sA = __shfl(sidA, mm, 64);
      int sB = __shfl(sidB, mm, 64);
      vrawA[r] = v2[(size_t)sA*16 + t];
      vrawB[r] = v2[(size_t)sB*16 + t];
    }

    bf16x8 auA0 = lds_read_chunk(lb32, (t   )*33 + q*4);
    bf16x8 auA1 = lds_read_chunk(lb32, (t   )*33 + 16 + q*4);
    bf16x8 auB0 = lds_read_chunk(lb32, (t+16)*33 + q*4);
    bf16x8 auB1 = lds_read_chunk(lb32, (t+16)*33 + 16 + q*4);

    // --- attn L2 -> w=exp ---
#pragma unroll
    for(int nt=0;nt<4;nt++){
      bf16x8 w0 = fb_load(FB, FB_A2+nt*2+0, lane);
      bf16x8 w1 = fb_load(FB, FB_A2+nt*2+1, lane);
      accA[nt] = __builtin_amdgcn_mfma_f32_16x16x32_bf16(auA0, w0, zero, 0,0,0);
      accA[nt] = __builtin_amdgcn_mfma_f32_16x16x32_bf16(auA1, w1, accA[nt], 0,0,0);
      accB[nt] = __builtin_amdgcn_mfma_f32_16x16x32_bf16(auB0, w0, zero, 0,0,0);
      accB[nt] = __builtin_amdgcn_mfma_f32_16x16x32_bf16(auB1, w1, accB[nt], 0,0,0);
    }
    float wvA[4][4], wvB[4][4], pdA[4][4], pdB[4][4];
#pragma unroll
    for(int nt=0;nt<4;nt++)
#pragma unroll
      for(int r=0;r<4;r++){
        wvA[nt][r] = ((tb + q*4 + r) < hi)      ? __expf(fminf(accA[nt][r] + ba2f[nt], 80.f)) : 0.f;
        wvB[nt][r] = ((tb + 16 + q*4 + r) < hi) ? __expf(fminf(accB[nt][r] + ba2f[nt], 80.f)) : 0.f;
      }
#pragma unroll
    for(int r=0;r<4;r++){
      float va[4] = { bf2f((u16)(vrawA[r].x & 0xffffu)), bf2f((u16)(vrawA[r].x >> 16)),
                      bf2f((u16)(vrawA[r].y & 0xffffu)), bf2f((u16)(vrawA[r].y >> 16)) };
      float vb[4] = { bf2f((u16)(vrawB[r].x & 0xffffu)), bf2f((u16)(vrawB[r].x >> 16)),
                      bf2f((u16)(vrawB[r].y & 0xffffu)), bf2f((u16)(vrawB[r].y >> 16)) };
#pragma unroll
      for(int nt=0;nt<4;nt++){
        pdA[r][nt] = va[nt] + bf2f(lfw[(     q*4+r)*66 + nt*16 + t]);
        pdB[r][nt] = vb[nt] + bf2f(lfw[(16 + q*4+r)*66 + nt*16 + t]);
      }
    }

    agg_tile(tb,      hi, lo, didA, wvA, pdA, cur_d, numP, SP, row_start, num, S, q, t);
    if(hasB)
      agg_tile(tb+16, hi, lo, didB, wvB, pdB, cur_d, numP, SP, row_start, num, S, q, t);
  }
  flushseg(cur_d, numP, SP, row_start, num, S, lo, hi, q, t);
}

// ---------- out = relu((num/S) @ Wout + bout), MFMA ----------
__global__ __launch_bounds__(256) void k_out_m(
  const float* __restrict__ num, const float* __restrict__ S,
  const float* __restrict__ Bf, const u16* __restrict__ FB,
  float* __restrict__ out, int N, int ntiles)
{
  int lane = threadIdx.x & 63, warp = threadIdx.x >> 6;
  int t = lane & 15, q = lane >> 4;
  int tile = blockIdx.x*4 + warp;
  if(tile >= ntiles) return;
  int r0 = tile*16;
  int row = r0 + t; if(row >= N) row = N-1;
  const float4* n4 = (const float4*)(num + (size_t)row*64);
  const float4* s4 = (const float4*)(S   + (size_t)row*64);
  bf16x8 af[2];
#pragma unroll
  for(int s=0;s<2;s++){
    float4 n0 = n4[s*8 + q*2], n1 = n4[s*8 + q*2 + 1];
    float4 s0 = s4[s*8 + q*2], s1 = s4[s*8 + q*2 + 1];
    af[s][0]=(short)f2bf(n0.x/(s0.x+1e-16f)); af[s][1]=(short)f2bf(n0.y/(s0.y+1e-16f));
    af[s][2]=(short)f2bf(n0.z/(s0.z+1e-16f)); af[s][3]=(short)f2bf(n0.w/(s0.w+1e-16f));
    af[s][4]=(short)f2bf(n1.x/(s1.x+1e-16f)); af[s][5]=(short)f2bf(n1.y/(s1.y+1e-16f));
    af[s][6]=(short)f2bf(n1.z/(s1.z+1e-16f)); af[s][7]=(short)f2bf(n1.w/(s1.w+1e-16f));
  }
  f32x4 zero = {0.f,0.f,0.f,0.f};
#pragma unroll
  for(int nt=0;nt<4;nt++){
    f32x4 a = __builtin_amdgcn_mfma_f32_16x16x32_bf16(af[0], fb_load(FB, FB_OUT+nt*2+0, lane), zero, 0,0,0);
    a = __builtin_amdgcn_mfma_f32_16x16x32_bf16(af[1], fb_load(FB, FB_OUT+nt*2+1, lane), a, 0,0,0);
    float b = Bf[320 + nt*16 + t];
#pragma unroll
    for(int r=0;r<4;r++){
      int rr = r0 + q*4 + r;
      if(rr < N) out[(size_t)rr*64 + nt*16 + t] = fmaxf(a[r] + b, 0.f);
    }
  }
}

extern "C" void kernel_launch(void* const* d_in, const int* in_sizes, int n_in,
                              void* d_out, int out_size, void* d_ws, size_t ws_size,
                              hipStream_t stream){
  const float* x   =(const float*)d_in[0];
  const float* pos =(const float*)d_in[1];
  const int*   ei  =(const int*)d_in[2];
  const float* Win =(const float*)d_in[3];  const float* bin=(const float*)d_in[4];
  const float* Wlin=(const float*)d_in[5];  const float* Wsrc=(const float*)d_in[6];
  const float* Wdst=(const float*)d_in[7];
  const float* Wp1 =(const float*)d_in[8];  const float* bp1=(const float*)d_in[9];
  const float* Wp2 =(const float*)d_in[10]; const float* bp2=(const float*)d_in[11];
  const float* Wa1 =(const float*)d_in[12]; const float* ba1=(const float*)d_in[13];
  const float* Wa2 =(const float*)d_in[14]; const float* ba2=(const float*)d_in[15];
  const float* Wout=(const float*)d_in[16]; const float* bout=(const float*)d_in[17];
  int N = in_sizes[0]/64;
  int E = in_sizes[2]/2;

  float* Bf   = (float*)d_ws;                      // 384 f32 (16B-aligned base)
  u16*   FB   = (u16*)(Bf + NBIAS);                // NFRAG*64*8 u16 (69632 B)
  u16*   vfb  = FB + (size_t)NFRAG*64*8;           // [N*64] bf16
  u16*   asb  = vfb + (size_t)N*64;                // [N*64] bf16 (16B-aligned: N*64*2 % 16 == 0)
  u16*   adb  = asb + (size_t)N*64;                // [N*64] bf16
  float* S    = (float*)(adb + (size_t)N*64);
  float* num  = S    + (size_t)N*64;
  int* deg       = (int*)(num + (size_t)N*64);
  int* cursor    = deg + N;
  int* row_start = cursor + N;
  int* bsum      = row_start + (N+1);
  int* bsoff     = bsum + 256;
  int2* pair     = (int2*)(bsoff + 256);

  int ntiles = (N+15)/16;
  int nsuper = (E+31)/32;
  int total_waves = 4096;
  int spw = (nsuper + total_waves - 1) / total_waves;
  int nwaves = (nsuper + spw - 1) / spw;
  int eblocks = (nwaves + 3) / 4;
  int nscb = (N+255)/256;

  hipMemsetAsync(deg, 0, (size_t)2*N*sizeof(int), stream);
  hipMemsetAsync(S, 0, (size_t)N*64*2*sizeof(float), stream);
  k_prep<<<dim3(19), dim3(256), 0, stream>>>(Win,Wlin,Wsrc,Wdst,Wp1,Wp2,Wa1,Wa2,Wout,
                                             bin,bp1,bp2,ba1,ba2,bout, Bf, FB);
  k_node_m<<<dim3((ntiles+3)/4), dim3(256), 0, stream>>>(x, Bf, FB, vfb, asb, adb, N, ntiles);
  k_hist<<<dim3((E+255)/256), dim3(256), 0, stream>>>(ei, deg, E);
  k_scanA<<<dim3(nscb), dim3(256), 0, stream>>>(deg, row_start, bsum, N);
  k_scanB<<<dim3(1),    dim3(256), 0, stream>>>(bsum, bsoff, row_start, nscb, N);
  k_scanC<<<dim3(nscb), dim3(256), 0, stream>>>(row_start, bsoff, N);
  k_scatter<<<dim3((E+255)/256), dim3(256), 0, stream>>>(ei, row_start, cursor, pair, E);
  k_edge_p2<<<dim3(eblocks), dim3(256), 0, stream>>>(row_start, pair, pos, Bf, FB,
                                                     vfb, asb, adb, S, num, E, nsuper, spw);
  k_out_m<<<dim3((ntiles+3)/4), dim3(256), 0, stream>>>(num, S, Bf, FB, (float*)d_out, N, ntiles);
}